// Round 6
// baseline (1967.265 us; speedup 1.0000x reference)
//
#include <hip/hip_runtime.h>
#include <math.h>

#define NN 100000
#define EE 1200000
#define DD 64
#define GG 128
#define LL 3
#define TOT (EE + NN)
#define NB_SCAN ((NN + 1023) / 1024)   // 98
#define BN_EPS 1e-5f
#define ENC_NEG_INF 0x007FFFFFu        // enc(-inf)
#define NPB_FC 128                      // nodes per block, k_bnfc (32/wave)
#define NPB_MM 256                      // nodes per block, k_lmm  (64/wave)
#define GSLOTS 16                       // per-block graph slots for seg-max
#define GRID_SPMM 2048
#define NT 8                            // nodes per wave-iteration (ILP)

__device__ __forceinline__ unsigned enc_f(float x) {
    unsigned u = __float_as_uint(x);
    return (u & 0x80000000u) ? ~u : (u | 0x80000000u);
}
__device__ __forceinline__ float dec_f(unsigned e) {
    return (e & 0x80000000u) ? __uint_as_float(e ^ 0x80000000u)
                             : __uint_as_float(~e);
}

// ---- graph preprocessing -------------------------------------------------

__global__ void k_init(int* cnt, float* stats, unsigned* ge) {
    int i = blockIdx.x * blockDim.x + threadIdx.x;
    if (i < NN) cnt[i] = 1;                 // self-loop
    if (i < LL * 2 * DD) stats[i] = 0.f;
    if (i < GG * DD) ge[i] = ENC_NEG_INF;
}

__global__ void k_count(const int* __restrict__ dst, int* cnt) {
    int e = blockIdx.x * blockDim.x + threadIdx.x;
    if (e < EE) atomicAdd(&cnt[dst[e]], 1);
}

__global__ void k_scan_a(const int* __restrict__ cnt, int* ptr, int* bsum) {
    __shared__ int s[1024];
    int t = threadIdx.x;
    int i = blockIdx.x * 1024 + t;
    int v = (i < NN) ? cnt[i] : 0;
    s[t] = v;
    __syncthreads();
    for (int off = 1; off < 1024; off <<= 1) {
        int add = (t >= off) ? s[t - off] : 0;
        __syncthreads();
        s[t] += add;
        __syncthreads();
    }
    if (i < NN) ptr[i] = s[t] - v;          // block-local exclusive
    if (t == 1023) bsum[blockIdx.x] = s[1023];
}

__global__ void k_scan_b(int* bsum, int* ptr) {
    if (blockIdx.x == 0 && threadIdx.x == 0) {
        int run = 0;
        for (int b = 0; b < NB_SCAN; b++) { int t = bsum[b]; bsum[b] = run; run += t; }
        ptr[NN] = TOT;
    }
}

__global__ void k_scan_c(int* ptr, int* cursor, const int* __restrict__ cnt,
                         float* dinv, const int* __restrict__ bsum) {
    int i = blockIdx.x * 1024 + threadIdx.x;
    if (i < NN) {
        int p = ptr[i] + bsum[blockIdx.x];
        ptr[i] = p;
        cursor[i] = p;
        dinv[i] = rsqrtf((float)cnt[i]);
    }
}

__global__ void k_fill(const int* __restrict__ src, const int* __restrict__ dst,
                       int* cursor, int* col) {
    int i = blockIdx.x * blockDim.x + threadIdx.x;
    if (i >= TOT) return;
    int s, d;
    if (i < EE) { s = src[i]; d = dst[i]; }
    else        { s = d = i - EE; }          // self-loops
    int pos = atomicAdd(&cursor[d], 1);
    col[pos] = s;
}

// ---- linear (+optional BN+ReLU): out[n,:] = act(h[n,:]) @ W --------------
// W in LDS; NT=8 nodes per wave-iteration amortizes each LDS weight read
// over 8 FMAs and gives 8 independent dep chains.

__global__ __launch_bounds__(256)
void k_lmm(const float* __restrict__ h, const float* __restrict__ stats,
           const float* __restrict__ g, const float* __restrict__ bb,
           const float* __restrict__ W, float* __restrict__ out, int apply_bn) {
    __shared__ float wl[DD * DD];           // 16 KB
    int t = threadIdx.x;
    for (int i = t; i < DD * DD / 4; i += 256)
        ((float4*)wl)[i] = ((const float4*)W)[i];
    __syncthreads();

    int lane = t & 63, wv = t >> 6;         // 4 waves/block
    int wn0 = blockIdx.x * NPB_MM + wv * (NPB_MM / 4);
    int wn1 = min(wn0 + NPB_MM / 4, NN);
    float sc = 1.f, sh = 0.f;
    if (apply_bn) {
        const float invN = 1.f / (float)NN;
        float mu = stats[lane] * invN;
        float var = stats[DD + lane] * invN - mu * mu;
        sc = g[lane] * rsqrtf(var + BN_EPS);
        sh = bb[lane] - mu * sc;
    }
    for (int nb = wn0; nb < wn1; nb += NT) {
        int cnt = min(NT, wn1 - nb);
        float y[NT];
        #pragma unroll
        for (int m = 0; m < NT; m++) {
            y[m] = (m < cnt) ? h[(nb + m) * DD + lane] : 0.f;
            if (apply_bn) y[m] = fmaxf(fmaf(y[m], sc, sh), 0.f);
        }
        float a[NT];
        #pragma unroll
        for (int m = 0; m < NT; m++) a[m] = 0.f;
        #pragma unroll
        for (int k = 0; k < DD; k++) {
            float w = wl[k * DD + lane];
            #pragma unroll
            for (int m = 0; m < NT; m++)
                a[m] = fmaf(__shfl(y[m], k, 64), w, a[m]);
        }
        #pragma unroll
        for (int m = 0; m < NT; m++)
            if (m < cnt) out[(nb + m) * DD + lane] = a[m];
    }
}

// ---- SpMM: agg[n,:] = sum_e norm_e * hw[col_e,:] + bias, + BN partials ---
// BN stats go to per-block partial buffer (no device-wide atomic contention).

__global__ void k_spmm(const float* __restrict__ hw, const int* __restrict__ ptr,
                       const int* __restrict__ col, const float* __restrict__ dinv,
                       const float* __restrict__ bias, float* __restrict__ agg,
                       float* __restrict__ pb) {
    int lane = threadIdx.x & 63;
    int wid = (blockIdx.x * blockDim.x + threadIdx.x) >> 6;
    int nw = (gridDim.x * blockDim.x) >> 6;
    int per = (NN + nw - 1) / nw;
    int n0 = wid * per, n1 = min(n0 + per, NN);
    float b = bias[lane];
    float s1 = 0.f, s2 = 0.f;
    for (int n = n0; n < n1; n++) {
        int p0 = ptr[n], p1 = ptr[n + 1];
        float dn = dinv[n];
        float acc0 = 0.f, acc1 = 0.f, acc2 = 0.f, acc3 = 0.f;
        for (int base = p0; base < p1; base += 64) {
            int cnt = min(64, p1 - base);
            int c_l = 0; float w_l = 0.f;
            if (lane < cnt) { c_l = col[base + lane]; w_l = dinv[c_l]; }
            int j = 0;
            for (; j + 3 < cnt; j += 4) {
                int   c0 = __shfl(c_l, j, 64),     c1 = __shfl(c_l, j + 1, 64);
                int   c2 = __shfl(c_l, j + 2, 64), c3 = __shfl(c_l, j + 3, 64);
                float w0 = __shfl(w_l, j, 64),     w1 = __shfl(w_l, j + 1, 64);
                float w2 = __shfl(w_l, j + 2, 64), w3 = __shfl(w_l, j + 3, 64);
                acc0 = fmaf(w0 * dn, hw[c0 * DD + lane], acc0);
                acc1 = fmaf(w1 * dn, hw[c1 * DD + lane], acc1);
                acc2 = fmaf(w2 * dn, hw[c2 * DD + lane], acc2);
                acc3 = fmaf(w3 * dn, hw[c3 * DD + lane], acc3);
            }
            for (; j < cnt; j++) {
                int   c0 = __shfl(c_l, j, 64);
                float w0 = __shfl(w_l, j, 64);
                acc0 = fmaf(w0 * dn, hw[c0 * DD + lane], acc0);
            }
        }
        float o = (acc0 + acc1) + (acc2 + acc3) + b;
        agg[n * DD + lane] = o;
        s1 += o;
        s2 = fmaf(o, o, s2);
    }
    __shared__ float red[512];
    int t = threadIdx.x;                     // blockDim == 256
    red[t] = s1;
    red[256 + t] = s2;
    __syncthreads();
    if (t < 64) {
        float a1 = red[t] + red[64 + t] + red[128 + t] + red[192 + t];
        float a2 = red[256 + t] + red[320 + t] + red[384 + t] + red[448 + t];
        pb[blockIdx.x * 2 * DD + t]      = a1;
        pb[blockIdx.x * 2 * DD + DD + t] = a2;
    }
}

// ---- reduce spmm partials -> stats (8 blocks, 8 atomics/address) ---------

__global__ void k_red(const float* __restrict__ pb, float* __restrict__ stats) {
    int t = threadIdx.x;                     // 128 threads: feature slot
    int b0 = blockIdx.x * (GRID_SPMM / 8);
    float s = 0.f;
    for (int b = b0; b < b0 + GRID_SPMM / 8; b++)
        s += pb[b * 2 * DD + t];
    atomicAdd(&stats[t], s);
}

// ---- last layer: BN+ReLU (node emb in-place) + fc1 + fc2 + seg-max -------
// fc1w/fc2w in LDS; NT=8 node tile; seg-max via per-block LDS graph slots.

__global__ __launch_bounds__(256)
void k_bnfc(float* __restrict__ h, const float* __restrict__ stats,
            const float* __restrict__ g, const float* __restrict__ bb,
            const float* __restrict__ fc1w, const float* __restrict__ fc1b,
            const float* __restrict__ fc2w, const float* __restrict__ fc2b,
            const int* __restrict__ batch, unsigned* ge) {
    __shared__ float w1[DD * DD];           // 16 KB
    __shared__ float w2[DD * DD];           // 16 KB
    __shared__ unsigned gmax[GSLOTS * DD];  // 4 KB
    int t = threadIdx.x;
    for (int i = t; i < DD * DD / 4; i += 256) {
        ((float4*)w1)[i] = ((const float4*)fc1w)[i];
        ((float4*)w2)[i] = ((const float4*)fc2w)[i];
    }
    for (int i = t; i < GSLOTS * DD; i += 256) gmax[i] = ENC_NEG_INF;
    __syncthreads();

    int lane = t & 63, wv = t >> 6;         // 4 waves/block
    int n0 = blockIdx.x * NPB_FC;
    int gbase = batch[n0];
    int wn0 = n0 + wv * (NPB_FC / 4);
    int wn1 = min(wn0 + NPB_FC / 4, NN);

    const float invN = 1.f / (float)NN;
    float mu = stats[lane] * invN;
    float var = stats[DD + lane] * invN - mu * mu;
    float sc = g[lane] * rsqrtf(var + BN_EPS);
    float sh = bb[lane] - mu * sc;
    float b1 = fc1b[lane], b2 = fc2b[lane];

    int curg = -1;
    float runmax = -INFINITY;
    for (int nb = wn0; nb < wn1; nb += NT) {
        int cnt = min(NT, wn1 - nb);
        float y[NT];
        #pragma unroll
        for (int m = 0; m < NT; m++) {
            if (m < cnt) {
                y[m] = fmaxf(fmaf(h[(nb + m) * DD + lane], sc, sh), 0.f);
                h[(nb + m) * DD + lane] = y[m];   // node_embeddings in-place
            } else y[m] = 0.f;
        }
        float o1[NT], o2[NT];
        #pragma unroll
        for (int m = 0; m < NT; m++) o1[m] = b1;
        #pragma unroll
        for (int k = 0; k < DD; k++) {
            float w = w1[k * DD + lane];
            #pragma unroll
            for (int m = 0; m < NT; m++)
                o1[m] = fmaf(__shfl(y[m], k, 64), w, o1[m]);
        }
        #pragma unroll
        for (int m = 0; m < NT; m++) o2[m] = b2;
        #pragma unroll
        for (int k = 0; k < DD; k++) {
            float w = w2[k * DD + lane];
            #pragma unroll
            for (int m = 0; m < NT; m++)
                o2[m] = fmaf(__shfl(o1[m], k, 64), w, o2[m]);
        }
        for (int m = 0; m < cnt; m++) {
            int g0 = batch[nb + m];          // wave-uniform (sorted batch)
            if (g0 != curg) {
                if (curg >= 0) {
                    int s = curg - gbase;
                    if (s < GSLOTS) atomicMax(&gmax[s * DD + lane], enc_f(runmax));
                    else            atomicMax(&ge[curg * DD + lane], enc_f(runmax));
                }
                curg = g0; runmax = -INFINITY;
            }
            runmax = fmaxf(runmax, o2[m]);
        }
    }
    if (curg >= 0) {
        int s = curg - gbase;
        if (s < GSLOTS) atomicMax(&gmax[s * DD + lane], enc_f(runmax));
        else            atomicMax(&ge[curg * DD + lane], enc_f(runmax));
    }
    __syncthreads();
    for (int s = wv; s < GSLOTS; s += 4) {   // drain touched slots
        unsigned v = gmax[s * DD + lane];
        if (__any(v != ENC_NEG_INF))
            atomicMax(&ge[(gbase + s) * DD + lane], v);
    }
}

// ---- readout: decode seg-max, fc3, log_softmax ---------------------------

__global__ void k_final(const unsigned* __restrict__ ge, const float* __restrict__ fc3w,
                        const float* __restrict__ fc3b, float* __restrict__ out_ge,
                        float* __restrict__ out_lg) {
    int g = blockIdx.x;          // 128 blocks
    int lane = threadIdx.x;      // 64 threads
    float f = dec_f(ge[g * DD + lane]);
    out_ge[g * DD + lane] = f;
    float v0 = f * fc3w[lane * 2 + 0];
    float v1 = f * fc3w[lane * 2 + 1];
    for (int off = 32; off; off >>= 1) {
        v0 += __shfl_xor(v0, off, 64);
        v1 += __shfl_xor(v1, off, 64);
    }
    if (lane == 0) {
        float l0 = v0 + fc3b[0], l1 = v1 + fc3b[1];
        float m = fmaxf(l0, l1);
        float lse = m + logf(expf(l0 - m) + expf(l1 - m));
        out_lg[g * 2 + 0] = l0 - lse;
        out_lg[g * 2 + 1] = l1 - lse;
    }
}

static inline size_t alup(size_t x) { return (x + 255) & ~(size_t)255; }

extern "C" void kernel_launch(void* const* d_in, const int* in_sizes, int n_in,
                              void* d_out, int out_size, void* d_ws, size_t ws_size,
                              hipStream_t stream) {
    const float* x      = (const float*)d_in[0];
    const int*   ei     = (const int*)d_in[1];
    const int*   srcI   = ei;
    const int*   dstI   = ei + EE;
    const int*   batch  = (const int*)d_in[2];
    const float* conv_w = (const float*)d_in[3];   // [3,64,64]
    const float* conv_b = (const float*)d_in[4];   // [3,64]
    const float* bn_g   = (const float*)d_in[5];
    const float* bn_b   = (const float*)d_in[6];
    const float* fc1w   = (const float*)d_in[7];
    const float* fc1b   = (const float*)d_in[8];
    const float* fc2w   = (const float*)d_in[9];
    const float* fc2b   = (const float*)d_in[10];
    const float* fc3w   = (const float*)d_in[11];
    const float* fc3b   = (const float*)d_in[12];

    char* w = (char*)d_ws;
    int*      cnt    = (int*)w;       w += alup(sizeof(int) * NN);
    int*      ptr    = (int*)w;       w += alup(sizeof(int) * (NN + 1));
    int*      cursor = (int*)w;       w += alup(sizeof(int) * NN);
    int*      bsum   = (int*)w;       w += alup(sizeof(int) * NB_SCAN);
    float*    dinv   = (float*)w;     w += alup(sizeof(float) * NN);
    int*      col    = (int*)w;       w += alup(sizeof(int) * TOT);
    float*    bufA   = (float*)w;     w += alup(sizeof(float) * NN * DD);
    float*    stats  = (float*)w;     w += alup(sizeof(float) * LL * 2 * DD);
    unsigned* ge     = (unsigned*)w;  w += alup(sizeof(unsigned) * GG * DD);
    float*    pb     = (float*)w;     w += alup(sizeof(float) * GRID_SPMM * 2 * DD);

    float* out     = (float*)d_out;
    float* agg     = out;              // reuse node-embedding region as scratch
    float* out_ge  = out + (size_t)NN * DD;
    float* out_lg  = out_ge + GG * DD;

    const int BLK = 256;
    const int GRID_MM = (NN + NPB_MM - 1) / NPB_MM;   // 391
    const int GRID_FC = (NN + NPB_FC - 1) / NPB_FC;   // 782

    hipLaunchKernelGGL(k_init,   dim3((NN + BLK - 1) / BLK), dim3(BLK), 0, stream,
                       cnt, stats, ge);
    hipLaunchKernelGGL(k_count,  dim3((EE + BLK - 1) / BLK), dim3(BLK), 0, stream,
                       dstI, cnt);
    hipLaunchKernelGGL(k_scan_a, dim3(NB_SCAN), dim3(1024), 0, stream, cnt, ptr, bsum);
    hipLaunchKernelGGL(k_scan_b, dim3(1), dim3(64), 0, stream, bsum, ptr);
    hipLaunchKernelGGL(k_scan_c, dim3(NB_SCAN), dim3(1024), 0, stream,
                       ptr, cursor, cnt, dinv, bsum);
    hipLaunchKernelGGL(k_fill,   dim3((TOT + BLK - 1) / BLK), dim3(BLK), 0, stream,
                       srcI, dstI, cursor, col);

    for (int l = 0; l < LL; l++) {
        // hw = act(h) @ Wl   (layer 0: no BN, h = x)
        hipLaunchKernelGGL(k_lmm, dim3(GRID_MM), dim3(BLK), 0, stream,
                           l == 0 ? x : agg,
                           stats + (l - 1) * 2 * DD,
                           bn_g + (l - 1) * DD, bn_b + (l - 1) * DD,
                           conv_w + l * DD * DD, bufA, l == 0 ? 0 : 1);
        hipLaunchKernelGGL(k_spmm, dim3(GRID_SPMM), dim3(BLK), 0, stream,
                           bufA, ptr, col, dinv, conv_b + l * DD, agg, pb);
        hipLaunchKernelGGL(k_red, dim3(8), dim3(2 * DD), 0, stream,
                           pb, stats + l * 2 * DD);
    }
    // BN2+ReLU (node emb in place) + fc1 + fc2 + segment-max
    hipLaunchKernelGGL(k_bnfc, dim3(GRID_FC), dim3(BLK), 0, stream,
                       agg, stats + 2 * 2 * DD, bn_g + 2 * DD, bn_b + 2 * DD,
                       fc1w, fc1b, fc2w, fc2b, batch, ge);
    hipLaunchKernelGGL(k_final, dim3(GG), dim3(64), 0, stream,
                       ge, fc3w, fc3b, out_ge, out_lg);
}

// Round 10
// 1123.312 us; speedup vs baseline: 1.7513x; 1.7513x over previous
//
#include <hip/hip_runtime.h>
#include <math.h>

#define NN 100000
#define EE 1200000
#define DD 64
#define GG 128
#define LL 3
#define TOT (EE + NN)
#define NB_SCAN ((NN + 1023) / 1024)   // 98
#define BN_EPS 1e-5f
#define ENC_NEG_INF 0x007FFFFFu        // enc(-inf)
#define NPB_FC 128                      // nodes per block, k_bnfc (32/wave)
#define NPB_MM 256                      // nodes per block, k_lmm  (64/wave)
#define GSLOTS 16                       // per-block graph slots for seg-max
#define GRID_SPMM 2048
#define NT 8                            // nodes per wave-iteration (static-indexed!)

__device__ __forceinline__ unsigned enc_f(float x) {
    unsigned u = __float_as_uint(x);
    return (u & 0x80000000u) ? ~u : (u | 0x80000000u);
}
__device__ __forceinline__ float dec_f(unsigned e) {
    return (e & 0x80000000u) ? __uint_as_float(e ^ 0x80000000u)
                             : __uint_as_float(~e);
}

// ---- graph preprocessing -------------------------------------------------

__global__ void k_init(int* cnt, float* stats, unsigned* ge) {
    int i = blockIdx.x * blockDim.x + threadIdx.x;
    if (i < NN) cnt[i] = 1;                 // self-loop
    if (i < LL * 2 * DD) stats[i] = 0.f;
    if (i < GG * DD) ge[i] = ENC_NEG_INF;
}

__global__ void k_count(const int* __restrict__ dst, int* cnt) {
    int e = blockIdx.x * blockDim.x + threadIdx.x;
    if (e < EE) atomicAdd(&cnt[dst[e]], 1);
}

__global__ void k_scan_a(const int* __restrict__ cnt, int* ptr, int* bsum) {
    __shared__ int s[1024];
    int t = threadIdx.x;
    int i = blockIdx.x * 1024 + t;
    int v = (i < NN) ? cnt[i] : 0;
    s[t] = v;
    __syncthreads();
    for (int off = 1; off < 1024; off <<= 1) {
        int add = (t >= off) ? s[t - off] : 0;
        __syncthreads();
        s[t] += add;
        __syncthreads();
    }
    if (i < NN) ptr[i] = s[t] - v;          // block-local exclusive
    if (t == 1023) bsum[blockIdx.x] = s[1023];
}

__global__ void k_scan_b(int* bsum, int* ptr) {
    if (blockIdx.x == 0 && threadIdx.x == 0) {
        int run = 0;
        for (int b = 0; b < NB_SCAN; b++) { int t = bsum[b]; bsum[b] = run; run += t; }
        ptr[NN] = TOT;
    }
}

__global__ void k_scan_c(int* ptr, int* cursor, const int* __restrict__ cnt,
                         float* dinv, const int* __restrict__ bsum) {
    int i = blockIdx.x * 1024 + threadIdx.x;
    if (i < NN) {
        int p = ptr[i] + bsum[blockIdx.x];
        ptr[i] = p;
        cursor[i] = p;
        dinv[i] = rsqrtf((float)cnt[i]);
    }
}

__global__ void k_fill(const int* __restrict__ src, const int* __restrict__ dst,
                       int* cursor, int* col) {
    int i = blockIdx.x * blockDim.x + threadIdx.x;
    if (i >= TOT) return;
    int s, d;
    if (i < EE) { s = src[i]; d = dst[i]; }
    else        { s = d = i - EE; }          // self-loops
    int pos = atomicAdd(&cursor[d], 1);
    col[pos] = s;
}

// ---- linear (+optional BN+ReLU): out[n,:] = act(h[n,:]) @ W --------------
// No shuffles: node tile staged in LDS, activations read as same-address
// float4 broadcasts, weights as stride-64 b32 (2 lanes/bank = free).
// All register arrays statically indexed (runtime cnt only in guards).

__global__ __launch_bounds__(256)
void k_lmm(const float* __restrict__ h, const float* __restrict__ stats,
           const float* __restrict__ g, const float* __restrict__ bb,
           const float* __restrict__ W, float* __restrict__ out, int apply_bn) {
    __shared__ float wl[DD * DD];           // 16 KB
    __shared__ float yt[4][NT][DD];         // 8 KB
    int t = threadIdx.x;
    for (int i = t; i < DD * DD / 4; i += 256)
        ((float4*)wl)[i] = ((const float4*)W)[i];
    __syncthreads();

    int lane = t & 63, wv = t >> 6;         // 4 waves/block
    int wn0 = blockIdx.x * NPB_MM + wv * (NPB_MM / 4);
    int wn1 = min(wn0 + NPB_MM / 4, NN);
    float sc = 1.f, sh = 0.f;
    if (apply_bn) {
        const float invN = 1.f / (float)NN;
        float mu = stats[lane] * invN;
        float var = stats[DD + lane] * invN - mu * mu;
        sc = g[lane] * rsqrtf(var + BN_EPS);
        sh = bb[lane] - mu * sc;
    }
    for (int nb = wn0; nb < wn1; nb += NT) {
        int cnt = min(NT, wn1 - nb);
        #pragma unroll
        for (int m = 0; m < NT; m++) {
            float y = 0.f;
            if (m < cnt) {
                y = h[(size_t)(nb + m) * DD + lane];
                if (apply_bn) y = fmaxf(fmaf(y, sc, sh), 0.f);
            }
            yt[wv][m][lane] = y;
        }
        float a[NT];
        #pragma unroll
        for (int m = 0; m < NT; m++) a[m] = 0.f;
        #pragma unroll
        for (int k0 = 0; k0 < DD; k0 += 4) {
            float w0 = wl[(k0 + 0) * DD + lane];
            float w1 = wl[(k0 + 1) * DD + lane];
            float w2 = wl[(k0 + 2) * DD + lane];
            float w3 = wl[(k0 + 3) * DD + lane];
            #pragma unroll
            for (int m = 0; m < NT; m++) {
                float4 yv = *(const float4*)&yt[wv][m][k0];   // broadcast read
                a[m] = fmaf(yv.x, w0, a[m]);
                a[m] = fmaf(yv.y, w1, a[m]);
                a[m] = fmaf(yv.z, w2, a[m]);
                a[m] = fmaf(yv.w, w3, a[m]);
            }
        }
        #pragma unroll
        for (int m = 0; m < NT; m++)
            if (m < cnt) out[(size_t)(nb + m) * DD + lane] = a[m];
    }
}

// ---- SpMM: agg[n,:] = sum_e norm_e * hw[col_e,:] + bias, + BN partials ---
// (round-4 measured inner loop; stats to per-block partials, no contention)

__global__ void k_spmm(const float* __restrict__ hw, const int* __restrict__ ptr,
                       const int* __restrict__ col, const float* __restrict__ dinv,
                       const float* __restrict__ bias, float* __restrict__ agg,
                       float* __restrict__ pb) {
    int lane = threadIdx.x & 63;
    int wid = (blockIdx.x * blockDim.x + threadIdx.x) >> 6;
    int nw = (gridDim.x * blockDim.x) >> 6;
    int per = (NN + nw - 1) / nw;
    int n0 = wid * per, n1 = min(n0 + per, NN);
    float b = bias[lane];
    float s1 = 0.f, s2 = 0.f;
    for (int n = n0; n < n1; n++) {
        int p0 = ptr[n], p1 = ptr[n + 1];
        float dn = dinv[n];
        float acc0 = 0.f, acc1 = 0.f;
        for (int base = p0; base < p1; base += 64) {
            int cnt = min(64, p1 - base);
            int c_l = 0; float w_l = 0.f;
            if (lane < cnt) { c_l = col[base + lane]; w_l = dinv[c_l]; }
            int j = 0;
            for (; j + 1 < cnt; j += 2) {
                int   c0 = __shfl(c_l, j, 64),     c1 = __shfl(c_l, j + 1, 64);
                float w0 = __shfl(w_l, j, 64),     w1 = __shfl(w_l, j + 1, 64);
                acc0 = fmaf(w0 * dn, hw[c0 * DD + lane], acc0);
                acc1 = fmaf(w1 * dn, hw[c1 * DD + lane], acc1);
            }
            if (j < cnt) {
                int   c0 = __shfl(c_l, j, 64);
                float w0 = __shfl(w_l, j, 64);
                acc0 = fmaf(w0 * dn, hw[c0 * DD + lane], acc0);
            }
        }
        float o = acc0 + acc1 + b;
        agg[n * DD + lane] = o;
        s1 += o;
        s2 = fmaf(o, o, s2);
    }
    __shared__ float red[512];
    int t = threadIdx.x;                     // blockDim == 256
    red[t] = s1;
    red[256 + t] = s2;
    __syncthreads();
    if (t < 64) {
        float a1 = red[t] + red[64 + t] + red[128 + t] + red[192 + t];
        float a2 = red[256 + t] + red[320 + t] + red[384 + t] + red[448 + t];
        pb[blockIdx.x * 2 * DD + t]      = a1;
        pb[blockIdx.x * 2 * DD + DD + t] = a2;
    }
}

// ---- reduce spmm partials -> stats (8 blocks, 8 atomics/address) ---------

__global__ void k_red(const float* __restrict__ pb, float* __restrict__ stats) {
    int t = threadIdx.x;                     // 128 threads: feature slot
    int b0 = blockIdx.x * (GRID_SPMM / 8);
    float s = 0.f;
    for (int b = b0; b < b0 + GRID_SPMM / 8; b++)
        s += pb[b * 2 * DD + t];
    atomicAdd(&stats[t], s);
}

// ---- last layer: BN+ReLU (node emb in-place) + fc1 + fc2 + seg-max -------
// Same broadcast-matvec structure, two chained matvecs (o1 reuses the yt
// tile), seg-max via per-block LDS graph slots, fully static reg indexing.

__global__ __launch_bounds__(256)
void k_bnfc(float* __restrict__ h, const float* __restrict__ stats,
            const float* __restrict__ g, const float* __restrict__ bb,
            const float* __restrict__ fc1w, const float* __restrict__ fc1b,
            const float* __restrict__ fc2w, const float* __restrict__ fc2b,
            const int* __restrict__ batch, unsigned* ge) {
    __shared__ float w1[DD * DD];           // 16 KB
    __shared__ float w2[DD * DD];           // 16 KB
    __shared__ float yt[4][NT][DD];         // 8 KB
    __shared__ unsigned gmax[GSLOTS * DD];  // 4 KB
    int t = threadIdx.x;
    for (int i = t; i < DD * DD / 4; i += 256) {
        ((float4*)w1)[i] = ((const float4*)fc1w)[i];
        ((float4*)w2)[i] = ((const float4*)fc2w)[i];
    }
    for (int i = t; i < GSLOTS * DD; i += 256) gmax[i] = ENC_NEG_INF;
    __syncthreads();

    int lane = t & 63, wv = t >> 6;         // 4 waves/block
    int n0 = blockIdx.x * NPB_FC;
    int gbase = batch[n0];
    int wn0 = n0 + wv * (NPB_FC / 4);
    int wn1 = min(wn0 + NPB_FC / 4, NN);

    const float invN = 1.f / (float)NN;
    float mu = stats[lane] * invN;
    float var = stats[DD + lane] * invN - mu * mu;
    float sc = g[lane] * rsqrtf(var + BN_EPS);
    float sh = bb[lane] - mu * sc;
    float b1 = fc1b[lane], b2 = fc2b[lane];

    int curg = -1;
    float runmax = -INFINITY;
    for (int nb = wn0; nb < wn1; nb += NT) {
        int cnt = min(NT, wn1 - nb);
        #pragma unroll
        for (int m = 0; m < NT; m++) {
            float y = 0.f;
            if (m < cnt) {
                y = fmaxf(fmaf(h[(size_t)(nb + m) * DD + lane], sc, sh), 0.f);
                h[(size_t)(nb + m) * DD + lane] = y;   // node_embeddings in-place
            }
            yt[wv][m][lane] = y;
        }
        float o1[NT];
        #pragma unroll
        for (int m = 0; m < NT; m++) o1[m] = b1;
        #pragma unroll
        for (int k0 = 0; k0 < DD; k0 += 4) {
            float wa = w1[(k0 + 0) * DD + lane];
            float wb = w1[(k0 + 1) * DD + lane];
            float wc = w1[(k0 + 2) * DD + lane];
            float wd = w1[(k0 + 3) * DD + lane];
            #pragma unroll
            for (int m = 0; m < NT; m++) {
                float4 yv = *(const float4*)&yt[wv][m][k0];
                o1[m] = fmaf(yv.x, wa, o1[m]);
                o1[m] = fmaf(yv.y, wb, o1[m]);
                o1[m] = fmaf(yv.z, wc, o1[m]);
                o1[m] = fmaf(yv.w, wd, o1[m]);
            }
        }
        #pragma unroll
        for (int m = 0; m < NT; m++) yt[wv][m][lane] = o1[m];
        float o2[NT];
        #pragma unroll
        for (int m = 0; m < NT; m++) o2[m] = b2;
        #pragma unroll
        for (int k0 = 0; k0 < DD; k0 += 4) {
            float wa = w2[(k0 + 0) * DD + lane];
            float wb = w2[(k0 + 1) * DD + lane];
            float wc = w2[(k0 + 2) * DD + lane];
            float wd = w2[(k0 + 3) * DD + lane];
            #pragma unroll
            for (int m = 0; m < NT; m++) {
                float4 yv = *(const float4*)&yt[wv][m][k0];
                o2[m] = fmaf(yv.x, wa, o2[m]);
                o2[m] = fmaf(yv.y, wb, o2[m]);
                o2[m] = fmaf(yv.z, wc, o2[m]);
                o2[m] = fmaf(yv.w, wd, o2[m]);
            }
        }
        #pragma unroll
        for (int m = 0; m < NT; m++) {       // static m; runtime guard only
            if (m < cnt) {
                int g0 = batch[nb + m];      // wave-uniform (sorted batch)
                if (g0 != curg) {
                    if (curg >= 0) {
                        int s = curg - gbase;
                        if (s < GSLOTS) atomicMax(&gmax[s * DD + lane], enc_f(runmax));
                        else            atomicMax(&ge[curg * DD + lane], enc_f(runmax));
                    }
                    curg = g0; runmax = -INFINITY;
                }
                runmax = fmaxf(runmax, o2[m]);
            }
        }
    }
    if (curg >= 0) {
        int s = curg - gbase;
        if (s < GSLOTS) atomicMax(&gmax[s * DD + lane], enc_f(runmax));
        else            atomicMax(&ge[curg * DD + lane], enc_f(runmax));
    }
    __syncthreads();
    for (int s = wv; s < GSLOTS; s += 4) {   // drain touched slots
        unsigned v = gmax[s * DD + lane];
        if (__any(v != ENC_NEG_INF))
            atomicMax(&ge[(gbase + s) * DD + lane], v);
    }
}

// ---- readout: decode seg-max, fc3, log_softmax ---------------------------

__global__ void k_final(const unsigned* __restrict__ ge, const float* __restrict__ fc3w,
                        const float* __restrict__ fc3b, float* __restrict__ out_ge,
                        float* __restrict__ out_lg) {
    int g = blockIdx.x;          // 128 blocks
    int lane = threadIdx.x;      // 64 threads
    float f = dec_f(ge[g * DD + lane]);
    out_ge[g * DD + lane] = f;
    float v0 = f * fc3w[lane * 2 + 0];
    float v1 = f * fc3w[lane * 2 + 1];
    for (int off = 32; off; off >>= 1) {
        v0 += __shfl_xor(v0, off, 64);
        v1 += __shfl_xor(v1, off, 64);
    }
    if (lane == 0) {
        float l0 = v0 + fc3b[0], l1 = v1 + fc3b[1];
        float m = fmaxf(l0, l1);
        float lse = m + logf(expf(l0 - m) + expf(l1 - m));
        out_lg[g * 2 + 0] = l0 - lse;
        out_lg[g * 2 + 1] = l1 - lse;
    }
}

static inline size_t alup(size_t x) { return (x + 255) & ~(size_t)255; }

extern "C" void kernel_launch(void* const* d_in, const int* in_sizes, int n_in,
                              void* d_out, int out_size, void* d_ws, size_t ws_size,
                              hipStream_t stream) {
    const float* x      = (const float*)d_in[0];
    const int*   ei     = (const int*)d_in[1];
    const int*   srcI   = ei;
    const int*   dstI   = ei + EE;
    const int*   batch  = (const int*)d_in[2];
    const float* conv_w = (const float*)d_in[3];   // [3,64,64]
    const float* conv_b = (const float*)d_in[4];   // [3,64]
    const float* bn_g   = (const float*)d_in[5];
    const float* bn_b   = (const float*)d_in[6];
    const float* fc1w   = (const float*)d_in[7];
    const float* fc1b   = (const float*)d_in[8];
    const float* fc2w   = (const float*)d_in[9];
    const float* fc2b   = (const float*)d_in[10];
    const float* fc3w   = (const float*)d_in[11];
    const float* fc3b   = (const float*)d_in[12];

    char* w = (char*)d_ws;
    int*      cnt    = (int*)w;       w += alup(sizeof(int) * NN);
    int*      ptr    = (int*)w;       w += alup(sizeof(int) * (NN + 1));
    int*      cursor = (int*)w;       w += alup(sizeof(int) * NN);
    int*      bsum   = (int*)w;       w += alup(sizeof(int) * NB_SCAN);
    float*    dinv   = (float*)w;     w += alup(sizeof(float) * NN);
    int*      col    = (int*)w;       w += alup(sizeof(int) * TOT);
    float*    bufA   = (float*)w;     w += alup(sizeof(float) * NN * DD);
    float*    stats  = (float*)w;     w += alup(sizeof(float) * LL * 2 * DD);
    unsigned* ge     = (unsigned*)w;  w += alup(sizeof(unsigned) * GG * DD);
    float*    pb     = (float*)w;     w += alup(sizeof(float) * GRID_SPMM * 2 * DD);

    float* out     = (float*)d_out;
    float* agg     = out;              // reuse node-embedding region as scratch
    float* out_ge  = out + (size_t)NN * DD;
    float* out_lg  = out_ge + GG * DD;

    const int BLK = 256;
    const int GRID_MM = (NN + NPB_MM - 1) / NPB_MM;   // 391
    const int GRID_FC = (NN + NPB_FC - 1) / NPB_FC;   // 782

    hipLaunchKernelGGL(k_init,   dim3((NN + BLK - 1) / BLK), dim3(BLK), 0, stream,
                       cnt, stats, ge);
    hipLaunchKernelGGL(k_count,  dim3((EE + BLK - 1) / BLK), dim3(BLK), 0, stream,
                       dstI, cnt);
    hipLaunchKernelGGL(k_scan_a, dim3(NB_SCAN), dim3(1024), 0, stream, cnt, ptr, bsum);
    hipLaunchKernelGGL(k_scan_b, dim3(1), dim3(64), 0, stream, bsum, ptr);
    hipLaunchKernelGGL(k_scan_c, dim3(NB_SCAN), dim3(1024), 0, stream,
                       ptr, cursor, cnt, dinv, bsum);
    hipLaunchKernelGGL(k_fill,   dim3((TOT + BLK - 1) / BLK), dim3(BLK), 0, stream,
                       srcI, dstI, cursor, col);

    for (int l = 0; l < LL; l++) {
        const float* st = (l == 0) ? stats : stats + (l - 1) * 2 * DD;
        const float* gg = (l == 0) ? bn_g : bn_g + (l - 1) * DD;
        const float* gb = (l == 0) ? bn_b : bn_b + (l - 1) * DD;
        hipLaunchKernelGGL(k_lmm, dim3(GRID_MM), dim3(BLK), 0, stream,
                           l == 0 ? x : agg, st, gg, gb,
                           conv_w + l * DD * DD, bufA, l == 0 ? 0 : 1);
        hipLaunchKernelGGL(k_spmm, dim3(GRID_SPMM), dim3(BLK), 0, stream,
                           bufA, ptr, col, dinv, conv_b + l * DD, agg, pb);
        hipLaunchKernelGGL(k_red, dim3(8), dim3(2 * DD), 0, stream,
                           pb, stats + l * 2 * DD);
    }
    // BN2+ReLU (node emb in place) + fc1 + fc2 + segment-max
    hipLaunchKernelGGL(k_bnfc, dim3(GRID_FC), dim3(BLK), 0, stream,
                       agg, stats + 2 * 2 * DD, bn_g + 2 * DD, bn_b + 2 * DD,
                       fc1w, fc1b, fc2w, fc2b, batch, ge);
    hipLaunchKernelGGL(k_final, dim3(GG), dim3(64), 0, stream,
                       ge, fc3w, fc3b, out_ge, out_lg);
}

// Round 12
// 627.339 us; speedup vs baseline: 3.1359x; 1.7906x over previous
//
#include <hip/hip_runtime.h>
#include <math.h>

#define NN 100000
#define EE 1200000
#define DD 64
#define GG 128
#define LL 3
#define TOT (EE + NN)
#define NB_SCAN ((NN + 1023) / 1024)   // 98
#define BN_EPS 1e-5f
#define ENC_NEG_INF 0x007FFFFFu        // enc(-inf)
#define NPB_FC 128                      // nodes per block, k_bnfc (32/wave)
#define NPB_MM 128                      // nodes per block, k_lmm  (32/wave)
#define GSLOTS 16                       // per-block graph slots for seg-max
#define GRID_SPMM 2048
#define NT 8                            // nodes per wave-iteration (static-indexed!)

__device__ __forceinline__ unsigned enc_f(float x) {
    unsigned u = __float_as_uint(x);
    return (u & 0x80000000u) ? ~u : (u | 0x80000000u);
}
__device__ __forceinline__ float dec_f(unsigned e) {
    return (e & 0x80000000u) ? __uint_as_float(e ^ 0x80000000u)
                             : __uint_as_float(~e);
}

// ---- graph preprocessing -------------------------------------------------

__global__ void k_init(int* cnt, float* stats, unsigned* ge) {
    int i = blockIdx.x * blockDim.x + threadIdx.x;
    if (i < NN) cnt[i] = 1;                 // self-loop
    if (i < LL * 2 * DD) stats[i] = 0.f;
    if (i < GG * DD) ge[i] = ENC_NEG_INF;
}

__global__ void k_count(const int* __restrict__ dst, int* cnt) {
    int e = blockIdx.x * blockDim.x + threadIdx.x;
    if (e < EE) atomicAdd(&cnt[dst[e]], 1);
}

__global__ void k_scan_a(const int* __restrict__ cnt, int* ptr, int* bsum) {
    __shared__ int s[1024];
    int t = threadIdx.x;
    int i = blockIdx.x * 1024 + t;
    int v = (i < NN) ? cnt[i] : 0;
    s[t] = v;
    __syncthreads();
    for (int off = 1; off < 1024; off <<= 1) {
        int add = (t >= off) ? s[t - off] : 0;
        __syncthreads();
        s[t] += add;
        __syncthreads();
    }
    if (i < NN) ptr[i] = s[t] - v;          // block-local exclusive
    if (t == 1023) bsum[blockIdx.x] = s[1023];
}

__global__ void k_scan_b(int* bsum, int* ptr) {
    if (blockIdx.x == 0 && threadIdx.x == 0) {
        int run = 0;
        for (int b = 0; b < NB_SCAN; b++) { int t = bsum[b]; bsum[b] = run; run += t; }
        ptr[NN] = TOT;
    }
}

__global__ void k_scan_c(int* ptr, int* cursor, const int* __restrict__ cnt,
                         float* dinv, const int* __restrict__ bsum) {
    int i = blockIdx.x * 1024 + threadIdx.x;
    if (i < NN) {
        int p = ptr[i] + bsum[blockIdx.x];
        ptr[i] = p;
        cursor[i] = p;
        dinv[i] = rsqrtf((float)cnt[i]);
    }
}

__global__ void k_fill(const int* __restrict__ src, const int* __restrict__ dst,
                       int* cursor, int* col) {
    int i = blockIdx.x * blockDim.x + threadIdx.x;
    if (i >= TOT) return;
    int s, d;
    if (i < EE) { s = src[i]; d = dst[i]; }
    else        { s = d = i - EE; }          // self-loops
    int pos = atomicAdd(&cursor[d], 1);
    col[pos] = s;
}

// ---- linear (+optional BN+ReLU): out[n,:] = act(h[n,:]) @ W --------------
// Broadcast-matvec: node tile in LDS, same-address float4 activation reads,
// stride-64 b32 weight reads. k0 loop kept rolled (#pragma unroll 1) so the
// live set stays ~60 VGPR — full unroll spilled 300 MB to scratch (round 10).

__global__ __launch_bounds__(256)
void k_lmm(const float* __restrict__ h, const float* __restrict__ stats,
           const float* __restrict__ g, const float* __restrict__ bb,
           const float* __restrict__ W, float* __restrict__ out, int apply_bn) {
    __shared__ float wl[DD * DD];           // 16 KB
    __shared__ float yt[4][NT][DD];         // 8 KB
    int t = threadIdx.x;
    for (int i = t; i < DD * DD / 4; i += 256)
        ((float4*)wl)[i] = ((const float4*)W)[i];
    __syncthreads();

    int lane = t & 63, wv = t >> 6;         // 4 waves/block
    int wn0 = blockIdx.x * NPB_MM + wv * (NPB_MM / 4);
    int wn1 = min(wn0 + NPB_MM / 4, NN);
    float sc = 1.f, sh = 0.f;
    if (apply_bn) {
        const float invN = 1.f / (float)NN;
        float mu = stats[lane] * invN;
        float var = stats[DD + lane] * invN - mu * mu;
        sc = g[lane] * rsqrtf(var + BN_EPS);
        sh = bb[lane] - mu * sc;
    }
    for (int nb = wn0; nb < wn1; nb += NT) {
        int cnt = min(NT, wn1 - nb);
        #pragma unroll
        for (int m = 0; m < NT; m++) {
            float y = 0.f;
            if (m < cnt) {
                y = h[(size_t)(nb + m) * DD + lane];
                if (apply_bn) y = fmaxf(fmaf(y, sc, sh), 0.f);
            }
            yt[wv][m][lane] = y;
        }
        float a[NT];
        #pragma unroll
        for (int m = 0; m < NT; m++) a[m] = 0.f;
        #pragma unroll 1
        for (int k0 = 0; k0 < DD; k0 += 4) {
            float w0 = wl[(k0 + 0) * DD + lane];
            float w1 = wl[(k0 + 1) * DD + lane];
            float w2 = wl[(k0 + 2) * DD + lane];
            float w3 = wl[(k0 + 3) * DD + lane];
            #pragma unroll
            for (int m = 0; m < NT; m++) {
                float4 yv = *(const float4*)&yt[wv][m][k0];   // broadcast read
                a[m] = fmaf(yv.x, w0, a[m]);
                a[m] = fmaf(yv.y, w1, a[m]);
                a[m] = fmaf(yv.z, w2, a[m]);
                a[m] = fmaf(yv.w, w3, a[m]);
            }
        }
        #pragma unroll
        for (int m = 0; m < NT; m++)
            if (m < cnt) out[(size_t)(nb + m) * DD + lane] = a[m];
    }
}

// ---- SpMM: agg[n,:] = sum_e norm_e * hw[col_e,:] + bias, + BN partials ---
// (round-4 measured inner loop; stats to per-block partials, no contention)

__global__ void k_spmm(const float* __restrict__ hw, const int* __restrict__ ptr,
                       const int* __restrict__ col, const float* __restrict__ dinv,
                       const float* __restrict__ bias, float* __restrict__ agg,
                       float* __restrict__ pb) {
    int lane = threadIdx.x & 63;
    int wid = (blockIdx.x * blockDim.x + threadIdx.x) >> 6;
    int nw = (gridDim.x * blockDim.x) >> 6;
    int per = (NN + nw - 1) / nw;
    int n0 = wid * per, n1 = min(n0 + per, NN);
    float b = bias[lane];
    float s1 = 0.f, s2 = 0.f;
    for (int n = n0; n < n1; n++) {
        int p0 = ptr[n], p1 = ptr[n + 1];
        float dn = dinv[n];
        float acc0 = 0.f, acc1 = 0.f;
        for (int base = p0; base < p1; base += 64) {
            int cnt = min(64, p1 - base);
            int c_l = 0; float w_l = 0.f;
            if (lane < cnt) { c_l = col[base + lane]; w_l = dinv[c_l]; }
            int j = 0;
            for (; j + 1 < cnt; j += 2) {
                int   c0 = __shfl(c_l, j, 64),     c1 = __shfl(c_l, j + 1, 64);
                float w0 = __shfl(w_l, j, 64),     w1 = __shfl(w_l, j + 1, 64);
                acc0 = fmaf(w0 * dn, hw[c0 * DD + lane], acc0);
                acc1 = fmaf(w1 * dn, hw[c1 * DD + lane], acc1);
            }
            if (j < cnt) {
                int   c0 = __shfl(c_l, j, 64);
                float w0 = __shfl(w_l, j, 64);
                acc0 = fmaf(w0 * dn, hw[c0 * DD + lane], acc0);
            }
        }
        float o = acc0 + acc1 + b;
        agg[n * DD + lane] = o;
        s1 += o;
        s2 = fmaf(o, o, s2);
    }
    __shared__ float red[512];
    int t = threadIdx.x;                     // blockDim == 256
    red[t] = s1;
    red[256 + t] = s2;
    __syncthreads();
    if (t < 64) {
        float a1 = red[t] + red[64 + t] + red[128 + t] + red[192 + t];
        float a2 = red[256 + t] + red[320 + t] + red[384 + t] + red[448 + t];
        pb[blockIdx.x * 2 * DD + t]      = a1;
        pb[blockIdx.x * 2 * DD + DD + t] = a2;
    }
}

// ---- reduce spmm partials -> stats (8 blocks, 8 atomics/address) ---------

__global__ void k_red(const float* __restrict__ pb, float* __restrict__ stats) {
    int t = threadIdx.x;                     // 128 threads: feature slot
    int b0 = blockIdx.x * (GRID_SPMM / 8);
    float s = 0.f;
    for (int b = b0; b < b0 + GRID_SPMM / 8; b++)
        s += pb[b * 2 * DD + t];
    atomicAdd(&stats[t], s);
}

// ---- last layer: BN+ReLU (node emb in-place) + fc1 + fc2 + seg-max -------
// Broadcast-matvec ×2 (o1 staged back into yt); rolled k0 loops keep VGPR
// ≤128; seg-max via per-block LDS graph slots (block = 128 sorted nodes).

__global__ __launch_bounds__(256)
void k_bnfc(float* __restrict__ h, const float* __restrict__ stats,
            const float* __restrict__ g, const float* __restrict__ bb,
            const float* __restrict__ fc1w, const float* __restrict__ fc1b,
            const float* __restrict__ fc2w, const float* __restrict__ fc2b,
            const int* __restrict__ batch, unsigned* ge) {
    __shared__ float w1[DD * DD];           // 16 KB
    __shared__ float w2[DD * DD];           // 16 KB
    __shared__ float yt[4][NT][DD];         // 8 KB
    __shared__ unsigned gmax[GSLOTS * DD];  // 4 KB
    int t = threadIdx.x;
    for (int i = t; i < DD * DD / 4; i += 256) {
        ((float4*)w1)[i] = ((const float4*)fc1w)[i];
        ((float4*)w2)[i] = ((const float4*)fc2w)[i];
    }
    for (int i = t; i < GSLOTS * DD; i += 256) gmax[i] = ENC_NEG_INF;
    __syncthreads();

    int lane = t & 63, wv = t >> 6;         // 4 waves/block
    int n0 = blockIdx.x * NPB_FC;
    int gbase = batch[n0];
    int wn0 = n0 + wv * (NPB_FC / 4);
    int wn1 = min(wn0 + NPB_FC / 4, NN);

    const float invN = 1.f / (float)NN;
    float mu = stats[lane] * invN;
    float var = stats[DD + lane] * invN - mu * mu;
    float sc = g[lane] * rsqrtf(var + BN_EPS);
    float sh = bb[lane] - mu * sc;
    float b1 = fc1b[lane], b2 = fc2b[lane];

    int curg = -1;
    float runmax = -INFINITY;
    for (int nb = wn0; nb < wn1; nb += NT) {
        int cnt = min(NT, wn1 - nb);
        #pragma unroll
        for (int m = 0; m < NT; m++) {
            float y = 0.f;
            if (m < cnt) {
                y = fmaxf(fmaf(h[(size_t)(nb + m) * DD + lane], sc, sh), 0.f);
                h[(size_t)(nb + m) * DD + lane] = y;   // node_embeddings in-place
            }
            yt[wv][m][lane] = y;
        }
        float o1[NT];
        #pragma unroll
        for (int m = 0; m < NT; m++) o1[m] = b1;
        #pragma unroll 1
        for (int k0 = 0; k0 < DD; k0 += 4) {
            float wa = w1[(k0 + 0) * DD + lane];
            float wb = w1[(k0 + 1) * DD + lane];
            float wc = w1[(k0 + 2) * DD + lane];
            float wd = w1[(k0 + 3) * DD + lane];
            #pragma unroll
            for (int m = 0; m < NT; m++) {
                float4 yv = *(const float4*)&yt[wv][m][k0];
                o1[m] = fmaf(yv.x, wa, o1[m]);
                o1[m] = fmaf(yv.y, wb, o1[m]);
                o1[m] = fmaf(yv.z, wc, o1[m]);
                o1[m] = fmaf(yv.w, wd, o1[m]);
            }
        }
        #pragma unroll
        for (int m = 0; m < NT; m++) yt[wv][m][lane] = o1[m];
        float o2[NT];
        #pragma unroll
        for (int m = 0; m < NT; m++) o2[m] = b2;
        #pragma unroll 1
        for (int k0 = 0; k0 < DD; k0 += 4) {
            float wa = w2[(k0 + 0) * DD + lane];
            float wb = w2[(k0 + 1) * DD + lane];
            float wc = w2[(k0 + 2) * DD + lane];
            float wd = w2[(k0 + 3) * DD + lane];
            #pragma unroll
            for (int m = 0; m < NT; m++) {
                float4 yv = *(const float4*)&yt[wv][m][k0];
                o2[m] = fmaf(yv.x, wa, o2[m]);
                o2[m] = fmaf(yv.y, wb, o2[m]);
                o2[m] = fmaf(yv.z, wc, o2[m]);
                o2[m] = fmaf(yv.w, wd, o2[m]);
            }
        }
        #pragma unroll
        for (int m = 0; m < NT; m++) {       // static m; runtime guard only
            if (m < cnt) {
                int g0 = batch[nb + m];      // wave-uniform (sorted batch)
                if (g0 != curg) {
                    if (curg >= 0) {
                        int s = curg - gbase;
                        if (s < GSLOTS) atomicMax(&gmax[s * DD + lane], enc_f(runmax));
                        else            atomicMax(&ge[curg * DD + lane], enc_f(runmax));
                    }
                    curg = g0; runmax = -INFINITY;
                }
                runmax = fmaxf(runmax, o2[m]);
            }
        }
    }
    if (curg >= 0) {
        int s = curg - gbase;
        if (s < GSLOTS) atomicMax(&gmax[s * DD + lane], enc_f(runmax));
        else            atomicMax(&ge[curg * DD + lane], enc_f(runmax));
    }
    __syncthreads();
    for (int s = wv; s < GSLOTS; s += 4) {   // drain touched slots
        unsigned v = gmax[s * DD + lane];
        if (__any(v != ENC_NEG_INF))
            atomicMax(&ge[(gbase + s) * DD + lane], v);
    }
}

// ---- readout: decode seg-max, fc3, log_softmax ---------------------------

__global__ void k_final(const unsigned* __restrict__ ge, const float* __restrict__ fc3w,
                        const float* __restrict__ fc3b, float* __restrict__ out_ge,
                        float* __restrict__ out_lg) {
    int g = blockIdx.x;          // 128 blocks
    int lane = threadIdx.x;      // 64 threads
    float f = dec_f(ge[g * DD + lane]);
    out_ge[g * DD + lane] = f;
    float v0 = f * fc3w[lane * 2 + 0];
    float v1 = f * fc3w[lane * 2 + 1];
    for (int off = 32; off; off >>= 1) {
        v0 += __shfl_xor(v0, off, 64);
        v1 += __shfl_xor(v1, off, 64);
    }
    if (lane == 0) {
        float l0 = v0 + fc3b[0], l1 = v1 + fc3b[1];
        float m = fmaxf(l0, l1);
        float lse = m + logf(expf(l0 - m) + expf(l1 - m));
        out_lg[g * 2 + 0] = l0 - lse;
        out_lg[g * 2 + 1] = l1 - lse;
    }
}

static inline size_t alup(size_t x) { return (x + 255) & ~(size_t)255; }

extern "C" void kernel_launch(void* const* d_in, const int* in_sizes, int n_in,
                              void* d_out, int out_size, void* d_ws, size_t ws_size,
                              hipStream_t stream) {
    const float* x      = (const float*)d_in[0];
    const int*   ei     = (const int*)d_in[1];
    const int*   srcI   = ei;
    const int*   dstI   = ei + EE;
    const int*   batch  = (const int*)d_in[2];
    const float* conv_w = (const float*)d_in[3];   // [3,64,64]
    const float* conv_b = (const float*)d_in[4];   // [3,64]
    const float* bn_g   = (const float*)d_in[5];
    const float* bn_b   = (const float*)d_in[6];
    const float* fc1w   = (const float*)d_in[7];
    const float* fc1b   = (const float*)d_in[8];
    const float* fc2w   = (const float*)d_in[9];
    const float* fc2b   = (const float*)d_in[10];
    const float* fc3w   = (const float*)d_in[11];
    const float* fc3b   = (const float*)d_in[12];

    char* w = (char*)d_ws;
    int*      cnt    = (int*)w;       w += alup(sizeof(int) * NN);
    int*      ptr    = (int*)w;       w += alup(sizeof(int) * (NN + 1));
    int*      cursor = (int*)w;       w += alup(sizeof(int) * NN);
    int*      bsum   = (int*)w;       w += alup(sizeof(int) * NB_SCAN);
    float*    dinv   = (float*)w;     w += alup(sizeof(float) * NN);
    int*      col    = (int*)w;       w += alup(sizeof(int) * TOT);
    float*    bufA   = (float*)w;     w += alup(sizeof(float) * NN * DD);
    float*    stats  = (float*)w;     w += alup(sizeof(float) * LL * 2 * DD);
    unsigned* ge     = (unsigned*)w;  w += alup(sizeof(unsigned) * GG * DD);
    float*    pb     = (float*)w;     w += alup(sizeof(float) * GRID_SPMM * 2 * DD);

    float* out     = (float*)d_out;
    float* agg     = out;              // reuse node-embedding region as scratch
    float* out_ge  = out + (size_t)NN * DD;
    float* out_lg  = out_ge + GG * DD;

    const int BLK = 256;
    const int GRID_MM = (NN + NPB_MM - 1) / NPB_MM;   // 782
    const int GRID_FC = (NN + NPB_FC - 1) / NPB_FC;   // 782

    hipLaunchKernelGGL(k_init,   dim3((NN + BLK - 1) / BLK), dim3(BLK), 0, stream,
                       cnt, stats, ge);
    hipLaunchKernelGGL(k_count,  dim3((EE + BLK - 1) / BLK), dim3(BLK), 0, stream,
                       dstI, cnt);
    hipLaunchKernelGGL(k_scan_a, dim3(NB_SCAN), dim3(1024), 0, stream, cnt, ptr, bsum);
    hipLaunchKernelGGL(k_scan_b, dim3(1), dim3(64), 0, stream, bsum, ptr);
    hipLaunchKernelGGL(k_scan_c, dim3(NB_SCAN), dim3(1024), 0, stream,
                       ptr, cursor, cnt, dinv, bsum);
    hipLaunchKernelGGL(k_fill,   dim3((TOT + BLK - 1) / BLK), dim3(BLK), 0, stream,
                       srcI, dstI, cursor, col);

    for (int l = 0; l < LL; l++) {
        const float* st = (l == 0) ? stats : stats + (l - 1) * 2 * DD;
        const float* gg = (l == 0) ? bn_g : bn_g + (l - 1) * DD;
        const float* gb = (l == 0) ? bn_b : bn_b + (l - 1) * DD;
        hipLaunchKernelGGL(k_lmm, dim3(GRID_MM), dim3(BLK), 0, stream,
                           l == 0 ? x : agg, st, gg, gb,
                           conv_w + l * DD * DD, bufA, l == 0 ? 0 : 1);
        hipLaunchKernelGGL(k_spmm, dim3(GRID_SPMM), dim3(BLK), 0, stream,
                           bufA, ptr, col, dinv, conv_b + l * DD, agg, pb);
        hipLaunchKernelGGL(k_red, dim3(8), dim3(2 * DD), 0, stream,
                           pb, stats + l * 2 * DD);
    }
    // BN2+ReLU (node emb in place) + fc1 + fc2 + segment-max
    hipLaunchKernelGGL(k_bnfc, dim3(GRID_FC), dim3(BLK), 0, stream,
                       agg, stats + 2 * 2 * DD, bn_g + 2 * DD, bn_b + 2 * DD,
                       fc1w, fc1b, fc2w, fc2b, batch, ge);
    hipLaunchKernelGGL(k_final, dim3(GG), dim3(64), 0, stream,
                       ge, fc3w, fc3b, out_ge, out_lg);
}

// Round 14
// 601.727 us; speedup vs baseline: 3.2694x; 1.0426x over previous
//
#include <hip/hip_runtime.h>
#include <hip/hip_bf16.h>
#include <math.h>

#define NN 100000
#define EE 1200000
#define DD 64
#define GG 128
#define LL 3
#define TOT (EE + NN)
#define NB_SCAN ((NN + 1023) / 1024)   // 98
#define BN_EPS 1e-5f
#define ENC_NEG_INF 0x007FFFFFu        // enc(-inf)
#define NPB_FC 128                      // nodes per block, k_bnfc (32/wave)
#define NPB_MM 128                      // nodes per block, k_lmm  (32/wave)
#define GSLOTS 16                       // per-block graph slots for seg-max
#define GRID_SPMM 2048
#define NT 8                            // nodes per wave-iteration (static-indexed!)

__device__ __forceinline__ unsigned enc_f(float x) {
    unsigned u = __float_as_uint(x);
    return (u & 0x80000000u) ? ~u : (u | 0x80000000u);
}
__device__ __forceinline__ float dec_f(unsigned e) {
    return (e & 0x80000000u) ? __uint_as_float(e ^ 0x80000000u)
                             : __uint_as_float(~e);
}

// ---- graph preprocessing -------------------------------------------------

__global__ void k_init(int* cnt, float* stats, unsigned* ge) {
    int i = blockIdx.x * blockDim.x + threadIdx.x;
    if (i < NN) cnt[i] = 1;                 // self-loop
    if (i < LL * 2 * DD) stats[i] = 0.f;
    if (i < GG * DD) ge[i] = ENC_NEG_INF;
}

__global__ void k_count(const int* __restrict__ dst, int* cnt) {
    int e = blockIdx.x * blockDim.x + threadIdx.x;
    if (e < EE) atomicAdd(&cnt[dst[e]], 1);
}

__global__ void k_scan_a(const int* __restrict__ cnt, int* ptr, int* bsum) {
    __shared__ int s[1024];
    int t = threadIdx.x;
    int i = blockIdx.x * 1024 + t;
    int v = (i < NN) ? cnt[i] : 0;
    s[t] = v;
    __syncthreads();
    for (int off = 1; off < 1024; off <<= 1) {
        int add = (t >= off) ? s[t - off] : 0;
        __syncthreads();
        s[t] += add;
        __syncthreads();
    }
    if (i < NN) ptr[i] = s[t] - v;          // block-local exclusive
    if (t == 1023) bsum[blockIdx.x] = s[1023];
}

__global__ void k_scan_b(int* bsum, int* ptr) {
    if (blockIdx.x == 0 && threadIdx.x == 0) {
        int run = 0;
        for (int b = 0; b < NB_SCAN; b++) { int t = bsum[b]; bsum[b] = run; run += t; }
        ptr[NN] = TOT;
    }
}

__global__ void k_scan_c(int* ptr, int* cursor, const int* __restrict__ cnt,
                         float* dinv, const int* __restrict__ bsum) {
    int i = blockIdx.x * 1024 + threadIdx.x;
    if (i < NN) {
        int p = ptr[i] + bsum[blockIdx.x];
        ptr[i] = p;
        cursor[i] = p;
        dinv[i] = rsqrtf((float)cnt[i]);
    }
}

__global__ void k_fill(const int* __restrict__ src, const int* __restrict__ dst,
                       int* cursor, int* col) {
    int i = blockIdx.x * blockDim.x + threadIdx.x;
    if (i >= TOT) return;
    int s, d;
    if (i < EE) { s = src[i]; d = dst[i]; }
    else        { s = d = i - EE; }          // self-loops
    int pos = atomicAdd(&cursor[d], 1);
    col[pos] = s;
}

// ---- linear (+optional BN+ReLU): out[n,:] = act(h[n,:]) @ W, bf16 out ----
// Broadcast-matvec: node tile in LDS, same-address float4 activation reads,
// stride-64 b32 weight reads. k0 loop kept rolled (#pragma unroll 1) so the
// live set stays ~60 VGPR — full unroll spilled 300 MB to scratch (round 10).
// Output staged as bf16: halves the SpMM gather traffic (128 B rows).

__global__ __launch_bounds__(256)
void k_lmm(const float* __restrict__ h, const float* __restrict__ stats,
           const float* __restrict__ g, const float* __restrict__ bb,
           const float* __restrict__ W, __hip_bfloat16* __restrict__ out,
           int apply_bn) {
    __shared__ float wl[DD * DD];           // 16 KB
    __shared__ float yt[4][NT][DD];         // 8 KB
    int t = threadIdx.x;
    for (int i = t; i < DD * DD / 4; i += 256)
        ((float4*)wl)[i] = ((const float4*)W)[i];
    __syncthreads();

    int lane = t & 63, wv = t >> 6;         // 4 waves/block
    int wn0 = blockIdx.x * NPB_MM + wv * (NPB_MM / 4);
    int wn1 = min(wn0 + NPB_MM / 4, NN);
    float sc = 1.f, sh = 0.f;
    if (apply_bn) {
        const float invN = 1.f / (float)NN;
        float mu = stats[lane] * invN;
        float var = stats[DD + lane] * invN - mu * mu;
        sc = g[lane] * rsqrtf(var + BN_EPS);
        sh = bb[lane] - mu * sc;
    }
    for (int nb = wn0; nb < wn1; nb += NT) {
        int cnt = min(NT, wn1 - nb);
        #pragma unroll
        for (int m = 0; m < NT; m++) {
            float y = 0.f;
            if (m < cnt) {
                y = h[(size_t)(nb + m) * DD + lane];
                if (apply_bn) y = fmaxf(fmaf(y, sc, sh), 0.f);
            }
            yt[wv][m][lane] = y;
        }
        float a[NT];
        #pragma unroll
        for (int m = 0; m < NT; m++) a[m] = 0.f;
        #pragma unroll 1
        for (int k0 = 0; k0 < DD; k0 += 4) {
            float w0 = wl[(k0 + 0) * DD + lane];
            float w1 = wl[(k0 + 1) * DD + lane];
            float w2 = wl[(k0 + 2) * DD + lane];
            float w3 = wl[(k0 + 3) * DD + lane];
            #pragma unroll
            for (int m = 0; m < NT; m++) {
                float4 yv = *(const float4*)&yt[wv][m][k0];   // broadcast read
                a[m] = fmaf(yv.x, w0, a[m]);
                a[m] = fmaf(yv.y, w1, a[m]);
                a[m] = fmaf(yv.z, w2, a[m]);
                a[m] = fmaf(yv.w, w3, a[m]);
            }
        }
        #pragma unroll
        for (int m = 0; m < NT; m++)
            if (m < cnt) out[(size_t)(nb + m) * DD + lane] = __float2bfloat16(a[m]);
    }
}

// ---- SpMM: agg[n,:] = sum_e norm_e * hw[col_e,:] + bias, + BN partials ---
// bf16 gathers (128 B rows); fp32 accumulate; stats to per-block partials.

__global__ void k_spmm(const __hip_bfloat16* __restrict__ hw,
                       const int* __restrict__ ptr,
                       const int* __restrict__ col, const float* __restrict__ dinv,
                       const float* __restrict__ bias, float* __restrict__ agg,
                       float* __restrict__ pb) {
    int lane = threadIdx.x & 63;
    int wid = (blockIdx.x * blockDim.x + threadIdx.x) >> 6;
    int nw = (gridDim.x * blockDim.x) >> 6;
    int per = (NN + nw - 1) / nw;
    int n0 = wid * per, n1 = min(n0 + per, NN);
    float b = bias[lane];
    float s1 = 0.f, s2 = 0.f;
    for (int n = n0; n < n1; n++) {
        int p0 = ptr[n], p1 = ptr[n + 1];
        float dn = dinv[n];
        float acc0 = 0.f, acc1 = 0.f;
        for (int base = p0; base < p1; base += 64) {
            int cnt = min(64, p1 - base);
            int c_l = 0; float w_l = 0.f;
            if (lane < cnt) { c_l = col[base + lane]; w_l = dinv[c_l]; }
            int j = 0;
            for (; j + 1 < cnt; j += 2) {
                int   c0 = __shfl(c_l, j, 64),     c1 = __shfl(c_l, j + 1, 64);
                float w0 = __shfl(w_l, j, 64),     w1 = __shfl(w_l, j + 1, 64);
                acc0 = fmaf(w0 * dn, __bfloat162float(hw[(size_t)c0 * DD + lane]), acc0);
                acc1 = fmaf(w1 * dn, __bfloat162float(hw[(size_t)c1 * DD + lane]), acc1);
            }
            if (j < cnt) {
                int   c0 = __shfl(c_l, j, 64);
                float w0 = __shfl(w_l, j, 64);
                acc0 = fmaf(w0 * dn, __bfloat162float(hw[(size_t)c0 * DD + lane]), acc0);
            }
        }
        float o = acc0 + acc1 + b;
        agg[n * DD + lane] = o;
        s1 += o;
        s2 = fmaf(o, o, s2);
    }
    __shared__ float red[512];
    int t = threadIdx.x;                     // blockDim == 256
    red[t] = s1;
    red[256 + t] = s2;
    __syncthreads();
    if (t < 64) {
        float a1 = red[t] + red[64 + t] + red[128 + t] + red[192 + t];
        float a2 = red[256 + t] + red[320 + t] + red[384 + t] + red[448 + t];
        pb[blockIdx.x * 2 * DD + t]      = a1;
        pb[blockIdx.x * 2 * DD + DD + t] = a2;
    }
}

// ---- reduce spmm partials -> stats (8 blocks, 8 atomics/address) ---------

__global__ void k_red(const float* __restrict__ pb, float* __restrict__ stats) {
    int t = threadIdx.x;                     // 128 threads: feature slot
    int b0 = blockIdx.x * (GRID_SPMM / 8);
    float s = 0.f;
    for (int b = b0; b < b0 + GRID_SPMM / 8; b++)
        s += pb[b * 2 * DD + t];
    atomicAdd(&stats[t], s);
}

// ---- last layer: BN+ReLU (node emb in-place) + fc1 + fc2 + seg-max -------
// Broadcast-matvec ×2 (o1 staged back into yt); rolled k0 loops keep VGPR
// ≤128; seg-max via per-block LDS graph slots (block = 128 sorted nodes).

__global__ __launch_bounds__(256)
void k_bnfc(float* __restrict__ h, const float* __restrict__ stats,
            const float* __restrict__ g, const float* __restrict__ bb,
            const float* __restrict__ fc1w, const float* __restrict__ fc1b,
            const float* __restrict__ fc2w, const float* __restrict__ fc2b,
            const int* __restrict__ batch, unsigned* ge) {
    __shared__ float w1[DD * DD];           // 16 KB
    __shared__ float w2[DD * DD];           // 16 KB
    __shared__ float yt[4][NT][DD];         // 8 KB
    __shared__ unsigned gmax[GSLOTS * DD];  // 4 KB
    int t = threadIdx.x;
    for (int i = t; i < DD * DD / 4; i += 256) {
        ((float4*)w1)[i] = ((const float4*)fc1w)[i];
        ((float4*)w2)[i] = ((const float4*)fc2w)[i];
    }
    for (int i = t; i < GSLOTS * DD; i += 256) gmax[i] = ENC_NEG_INF;
    __syncthreads();

    int lane = t & 63, wv = t >> 6;         // 4 waves/block
    int n0 = blockIdx.x * NPB_FC;
    int gbase = batch[n0];
    int wn0 = n0 + wv * (NPB_FC / 4);
    int wn1 = min(wn0 + NPB_FC / 4, NN);

    const float invN = 1.f / (float)NN;
    float mu = stats[lane] * invN;
    float var = stats[DD + lane] * invN - mu * mu;
    float sc = g[lane] * rsqrtf(var + BN_EPS);
    float sh = bb[lane] - mu * sc;
    float b1 = fc1b[lane], b2 = fc2b[lane];

    int curg = -1;
    float runmax = -INFINITY;
    for (int nb = wn0; nb < wn1; nb += NT) {
        int cnt = min(NT, wn1 - nb);
        #pragma unroll
        for (int m = 0; m < NT; m++) {
            float y = 0.f;
            if (m < cnt) {
                y = fmaxf(fmaf(h[(size_t)(nb + m) * DD + lane], sc, sh), 0.f);
                h[(size_t)(nb + m) * DD + lane] = y;   // node_embeddings in-place
            }
            yt[wv][m][lane] = y;
        }
        float o1[NT];
        #pragma unroll
        for (int m = 0; m < NT; m++) o1[m] = b1;
        #pragma unroll 1
        for (int k0 = 0; k0 < DD; k0 += 4) {
            float wa = w1[(k0 + 0) * DD + lane];
            float wb = w1[(k0 + 1) * DD + lane];
            float wc = w1[(k0 + 2) * DD + lane];
            float wd = w1[(k0 + 3) * DD + lane];
            #pragma unroll
            for (int m = 0; m < NT; m++) {
                float4 yv = *(const float4*)&yt[wv][m][k0];
                o1[m] = fmaf(yv.x, wa, o1[m]);
                o1[m] = fmaf(yv.y, wb, o1[m]);
                o1[m] = fmaf(yv.z, wc, o1[m]);
                o1[m] = fmaf(yv.w, wd, o1[m]);
            }
        }
        #pragma unroll
        for (int m = 0; m < NT; m++) yt[wv][m][lane] = o1[m];
        float o2[NT];
        #pragma unroll
        for (int m = 0; m < NT; m++) o2[m] = b2;
        #pragma unroll 1
        for (int k0 = 0; k0 < DD; k0 += 4) {
            float wa = w2[(k0 + 0) * DD + lane];
            float wb = w2[(k0 + 1) * DD + lane];
            float wc = w2[(k0 + 2) * DD + lane];
            float wd = w2[(k0 + 3) * DD + lane];
            #pragma unroll
            for (int m = 0; m < NT; m++) {
                float4 yv = *(const float4*)&yt[wv][m][k0];
                o2[m] = fmaf(yv.x, wa, o2[m]);
                o2[m] = fmaf(yv.y, wb, o2[m]);
                o2[m] = fmaf(yv.z, wc, o2[m]);
                o2[m] = fmaf(yv.w, wd, o2[m]);
            }
        }
        #pragma unroll
        for (int m = 0; m < NT; m++) {       // static m; runtime guard only
            if (m < cnt) {
                int g0 = batch[nb + m];      // wave-uniform (sorted batch)
                if (g0 != curg) {
                    if (curg >= 0) {
                        int s = curg - gbase;
                        if (s < GSLOTS) atomicMax(&gmax[s * DD + lane], enc_f(runmax));
                        else            atomicMax(&ge[curg * DD + lane], enc_f(runmax));
                    }
                    curg = g0; runmax = -INFINITY;
                }
                runmax = fmaxf(runmax, o2[m]);
            }
        }
    }
    if (curg >= 0) {
        int s = curg - gbase;
        if (s < GSLOTS) atomicMax(&gmax[s * DD + lane], enc_f(runmax));
        else            atomicMax(&ge[curg * DD + lane], enc_f(runmax));
    }
    __syncthreads();
    for (int s = wv; s < GSLOTS; s += 4) {   // drain touched slots
        unsigned v = gmax[s * DD + lane];
        if (__any(v != ENC_NEG_INF))
            atomicMax(&ge[(gbase + s) * DD + lane], v);
    }
}

// ---- readout: decode seg-max, fc3, log_softmax ---------------------------

__global__ void k_final(const unsigned* __restrict__ ge, const float* __restrict__ fc3w,
                        const float* __restrict__ fc3b, float* __restrict__ out_ge,
                        float* __restrict__ out_lg) {
    int g = blockIdx.x;          // 128 blocks
    int lane = threadIdx.x;      // 64 threads
    float f = dec_f(ge[g * DD + lane]);
    out_ge[g * DD + lane] = f;
    float v0 = f * fc3w[lane * 2 + 0];
    float v1 = f * fc3w[lane * 2 + 1];
    for (int off = 32; off; off >>= 1) {
        v0 += __shfl_xor(v0, off, 64);
        v1 += __shfl_xor(v1, off, 64);
    }
    if (lane == 0) {
        float l0 = v0 + fc3b[0], l1 = v1 + fc3b[1];
        float m = fmaxf(l0, l1);
        float lse = m + logf(expf(l0 - m) + expf(l1 - m));
        out_lg[g * 2 + 0] = l0 - lse;
        out_lg[g * 2 + 1] = l1 - lse;
    }
}

static inline size_t alup(size_t x) { return (x + 255) & ~(size_t)255; }

extern "C" void kernel_launch(void* const* d_in, const int* in_sizes, int n_in,
                              void* d_out, int out_size, void* d_ws, size_t ws_size,
                              hipStream_t stream) {
    const float* x      = (const float*)d_in[0];
    const int*   ei     = (const int*)d_in[1];
    const int*   srcI   = ei;
    const int*   dstI   = ei + EE;
    const int*   batch  = (const int*)d_in[2];
    const float* conv_w = (const float*)d_in[3];   // [3,64,64]
    const float* conv_b = (const float*)d_in[4];   // [3,64]
    const float* bn_g   = (const float*)d_in[5];
    const float* bn_b   = (const float*)d_in[6];
    const float* fc1w   = (const float*)d_in[7];
    const float* fc1b   = (const float*)d_in[8];
    const float* fc2w   = (const float*)d_in[9];
    const float* fc2b   = (const float*)d_in[10];
    const float* fc3w   = (const float*)d_in[11];
    const float* fc3b   = (const float*)d_in[12];

    char* w = (char*)d_ws;
    int*      cnt    = (int*)w;       w += alup(sizeof(int) * NN);
    int*      ptr    = (int*)w;       w += alup(sizeof(int) * (NN + 1));
    int*      cursor = (int*)w;       w += alup(sizeof(int) * NN);
    int*      bsum   = (int*)w;       w += alup(sizeof(int) * NB_SCAN);
    float*    dinv   = (float*)w;     w += alup(sizeof(float) * NN);
    int*      col    = (int*)w;       w += alup(sizeof(int) * TOT);
    __hip_bfloat16* bufA = (__hip_bfloat16*)w;
                                      w += alup(sizeof(__hip_bfloat16) * NN * DD);
    float*    stats  = (float*)w;     w += alup(sizeof(float) * LL * 2 * DD);
    unsigned* ge     = (unsigned*)w;  w += alup(sizeof(unsigned) * GG * DD);
    float*    pb     = (float*)w;     w += alup(sizeof(float) * GRID_SPMM * 2 * DD);

    float* out     = (float*)d_out;
    float* agg     = out;              // reuse node-embedding region as scratch
    float* out_ge  = out + (size_t)NN * DD;
    float* out_lg  = out_ge + GG * DD;

    const int BLK = 256;
    const int GRID_MM = (NN + NPB_MM - 1) / NPB_MM;   // 782
    const int GRID_FC = (NN + NPB_FC - 1) / NPB_FC;   // 782

    hipLaunchKernelGGL(k_init,   dim3((NN + BLK - 1) / BLK), dim3(BLK), 0, stream,
                       cnt, stats, ge);
    hipLaunchKernelGGL(k_count,  dim3((EE + BLK - 1) / BLK), dim3(BLK), 0, stream,
                       dstI, cnt);
    hipLaunchKernelGGL(k_scan_a, dim3(NB_SCAN), dim3(1024), 0, stream, cnt, ptr, bsum);
    hipLaunchKernelGGL(k_scan_b, dim3(1), dim3(64), 0, stream, bsum, ptr);
    hipLaunchKernelGGL(k_scan_c, dim3(NB_SCAN), dim3(1024), 0, stream,
                       ptr, cursor, cnt, dinv, bsum);
    hipLaunchKernelGGL(k_fill,   dim3((TOT + BLK - 1) / BLK), dim3(BLK), 0, stream,
                       srcI, dstI, cursor, col);

    for (int l = 0; l < LL; l++) {
        const float* st = (l == 0) ? stats : stats + (l - 1) * 2 * DD;
        const float* gg = (l == 0) ? bn_g : bn_g + (l - 1) * DD;
        const float* gb = (l == 0) ? bn_b : bn_b + (l - 1) * DD;
        hipLaunchKernelGGL(k_lmm, dim3(GRID_MM), dim3(BLK), 0, stream,
                           l == 0 ? x : agg, st, gg, gb,
                           conv_w + l * DD * DD, bufA, l == 0 ? 0 : 1);
        hipLaunchKernelGGL(k_spmm, dim3(GRID_SPMM), dim3(BLK), 0, stream,
                           bufA, ptr, col, dinv, conv_b + l * DD, agg, pb);
        hipLaunchKernelGGL(k_red, dim3(8), dim3(2 * DD), 0, stream,
                           pb, stats + l * 2 * DD);
    }
    // BN2+ReLU (node emb in place) + fc1 + fc2 + segment-max
    hipLaunchKernelGGL(k_bnfc, dim3(GRID_FC), dim3(BLK), 0, stream,
                       agg, stats + 2 * 2 * DD, bn_g + 2 * DD, bn_b + 2 * DD,
                       fc1w, fc1b, fc2w, fc2b, batch, ge);
    hipLaunchKernelGGL(k_final, dim3(GG), dim3(64), 0, stream,
                       ge, fc3w, fc3b, out_ge, out_lg);
}